// Round 1
// baseline (833.580 us; speedup 1.0000x reference)
//
#include <hip/hip_runtime.h>
#include <stdint.h>
#include <math.h>

#define NB 16384      // batch
#define NSEQ 32       // sequence length
#define NV 1001       // vocab (V+1)
#define NROWS 32768   // 2 * NB flattened rows

// ---------------- threefry2x32 (JAX-exact) ----------------
__device__ __forceinline__ void tf2x32(uint32_t k0, uint32_t k1,
                                       uint32_t x0, uint32_t x1,
                                       uint32_t& o0, uint32_t& o1) {
  const uint32_t ks0 = k0, ks1 = k1, ks2 = k0 ^ k1 ^ 0x1BD11BDAu;
  x0 += ks0; x1 += ks1;
  const int rA[4] = {13, 15, 26, 6};
  const int rB[4] = {17, 29, 16, 24};
#pragma unroll
  for (int i = 0; i < 4; ++i) { x0 += x1; x1 = (x1 << rA[i]) | (x1 >> (32 - rA[i])); x1 ^= x0; }
  x0 += ks1; x1 += ks2 + 1u;
#pragma unroll
  for (int i = 0; i < 4; ++i) { x0 += x1; x1 = (x1 << rB[i]) | (x1 >> (32 - rB[i])); x1 ^= x0; }
  x0 += ks2; x1 += ks0 + 2u;
#pragma unroll
  for (int i = 0; i < 4; ++i) { x0 += x1; x1 = (x1 << rA[i]) | (x1 >> (32 - rA[i])); x1 ^= x0; }
  x0 += ks0; x1 += ks1 + 3u;
#pragma unroll
  for (int i = 0; i < 4; ++i) { x0 += x1; x1 = (x1 << rB[i]) | (x1 >> (32 - rB[i])); x1 ^= x0; }
  x0 += ks1; x1 += ks2 + 4u;
#pragma unroll
  for (int i = 0; i < 4; ++i) { x0 += x1; x1 = (x1 << rA[i]) | (x1 >> (32 - rA[i])); x1 ^= x0; }
  o0 = x0 + ks2; o1 = x1 + ks0 + 5u;
}

// bits -> gumbel, exactly mirroring jax uniform(minval=tiny)+gumbel in fp32
__device__ __forceinline__ float gumbel_from_bits(uint32_t bits) {
  uint32_t fb = (bits >> 9) | 0x3f800000u;
  float u = __uint_as_float(fb) - 1.0f;
  u = fmaxf(u, 1.17549435e-38f);   // == u*(1-tiny)+tiny then max(tiny,.) in fp32
  return -logf(-logf(u));
}

// categorical sample + log_prob. partitionable random_bits: flat j -> xor of pair
template <int C>
__device__ __forceinline__ void samp(uint32_t k0, uint32_t k1, int b,
                                     const float* logits, int& sOut, float& lpOut) {
  float m = -3.4e38f;
#pragma unroll
  for (int c = 0; c < C; ++c) m = fmaxf(m, logits[c]);
  float se = 0.f;
#pragma unroll
  for (int c = 0; c < C; ++c) se += expf(logits[c] - m);
  const float lse = logf(se);
  int best = 0; float bz = -3.4e38f, bl = 0.f;
#pragma unroll
  for (int c = 0; c < C; ++c) {
    uint32_t o0, o1; tf2x32(k0, k1, 0u, (uint32_t)(b * C + c), o0, o1);
    float z = logits[c] + gumbel_from_bits(o0 ^ o1);
    if (z > bz) { bz = z; best = c; bl = logits[c]; }   // strict > == argmax first-max
  }
  sOut = best;
  lpOut = (bl - m) - lse;
}

__device__ __forceinline__ float sigm(float x) { return 1.0f / (1.0f + __expf(-x)); }
__device__ __forceinline__ float tanh_(float x) {
  float e = __expf(2.0f * x);
  return 1.0f - 2.0f / (e + 1.0f);
}

__device__ __forceinline__ float dot64(const float* __restrict__ w, const float* h) {
  float a = 0.f;
#pragma unroll
  for (int k = 0; k < 64; ++k) a = fmaf(w[k], h[k], a);
  return a;
}

// ---------------- kernel A: embedW precompute + W_hh transpose ----------------
// embedW[v][j] = b_ih[j] + b_hh[j] + sum_k embed[v][k]*W_ih[j][k]   (j in [0,256))
// WT[k][j] = W_hh[j][k]
__global__ __launch_bounds__(256) void k_prep(
    const float* __restrict__ embed, const float* __restrict__ W_ih,
    const float* __restrict__ W_hh, const float* __restrict__ b_ih,
    const float* __restrict__ b_hh, float* __restrict__ embedW,
    float* __restrict__ WT) {
  if (blockIdx.x >= NV) {
    int idx = (blockIdx.x - NV) * 256 + threadIdx.x;  // 0..16383
    int k = idx >> 8, j = idx & 255;
    WT[idx] = W_hh[j * 64 + k];
    return;
  }
  __shared__ float er[64];
  int v = blockIdx.x;
  if (threadIdx.x < 64) er[threadIdx.x] = embed[v * 64 + threadIdx.x];
  __syncthreads();
  int j = threadIdx.x;
  float a = b_ih[j] + b_hh[j];
#pragma unroll
  for (int k = 0; k < 64; ++k) a = fmaf(W_ih[j * 64 + k], er[k], a);
  embedW[v * 256 + j] = a;
}

// ---------------- kernel B: LSTM over both sequences ----------------
// grid 512 WGs x 512 threads. WG covers 64 batch rows (lane = row).
// wave w (8 per WG) owns hidden units [8w, 8w+8): computes i,f,g,o for those units.
// W^T read wave-uniformly (scalar loads); h lives in LDS [unit][row]; c in regs.
__global__ __launch_bounds__(512) void k_lstm(
    const int* __restrict__ inst0, const int* __restrict__ inst1,
    const float* __restrict__ embedW, const float* __restrict__ WT,
    float* __restrict__ hT) {
  __shared__ float hbuf[64 * 64];  // [unit][row] 16 KB
  const int tid = threadIdx.x;
  const int lane = tid & 63;
  const int wave = __builtin_amdgcn_readfirstlane(tid >> 6);  // 0..7, wave-uniform
  const int u0 = wave * 8;
  const int base = blockIdx.x * 64;
  const int flat = base + lane;
  const int s = base >> 14;        // 0: inst0, 1: inst1 (uniform per WG)
  const int b = flat & (NB - 1);
  const int* __restrict__ inst = s ? inst1 : inst0;

  for (int i = tid; i < 64 * 64; i += 512) hbuf[i] = 0.f;
  float c[8];
#pragma unroll
  for (int i = 0; i < 8; ++i) c[i] = 0.f;
  __syncthreads();

  for (int t = 0; t < NSEQ; ++t) {
    const int vidx = inst[b * NSEQ + t];
    const float* __restrict__ erow = embedW + vidx * 256 + u0;
    float acc[4][8];
#pragma unroll
    for (int g = 0; g < 4; ++g) {
      float4 a0 = *reinterpret_cast<const float4*>(erow + g * 64);
      float4 a1 = *reinterpret_cast<const float4*>(erow + g * 64 + 4);
      acc[g][0] = a0.x; acc[g][1] = a0.y; acc[g][2] = a0.z; acc[g][3] = a0.w;
      acc[g][4] = a1.x; acc[g][5] = a1.y; acc[g][6] = a1.z; acc[g][7] = a1.w;
    }
#pragma unroll 4
    for (int k = 0; k < 64; ++k) {
      const float hk = hbuf[k * 64 + lane];
      const float* __restrict__ w = WT + k * 256 + u0;  // wave-uniform -> s_load
#pragma unroll
      for (int g = 0; g < 4; ++g)
#pragma unroll
        for (int i = 0; i < 8; ++i)
          acc[g][i] = fmaf(w[g * 64 + i], hk, acc[g][i]);
    }
    __syncthreads();  // all reads of hbuf done before overwrite
#pragma unroll
    for (int i = 0; i < 8; ++i) {
      const float iv = acc[0][i], fv = acc[1][i], gv = acc[2][i], ov = acc[3][i];
      const float ci = sigm(fv) * c[i] + sigm(iv) * tanh_(gv);
      c[i] = ci;
      hbuf[(u0 + i) * 64 + lane] = sigm(ov) * tanh_(ci);
    }
    __syncthreads();  // new h visible
  }
  // store h transposed: hT[u][flat]  (coalesced here and in k_heads)
#pragma unroll
  for (int i = 0; i < 8; ++i)
    hT[(u0 + i) * NROWS + flat] = hbuf[(u0 + i) * 64 + lane];
}

// ---------------- kernel C: heads + sampling + rewards ----------------
__global__ __launch_bounds__(256) void k_heads(
    const int* __restrict__ canvas0, const int* __restrict__ canvas1,
    const int* __restrict__ ref,
    const float* __restrict__ Wc, const float* __restrict__ bc,
    const float* __restrict__ Ws, const float* __restrict__ bs,
    const float* __restrict__ Wl, const float* __restrict__ bl,
    const float* __restrict__ Wr1, const float* __restrict__ br1,
    const float* __restrict__ Wr2, const float* __restrict__ br2,
    const float* __restrict__ Wp, const float* __restrict__ bp,
    const float* __restrict__ hT, float* __restrict__ out) {
  const int b = blockIdx.x * 256 + threadIdx.x;

  // subkeys of key(42): foldlike/partitionable split -> key i = threefry((0,42),(0,i))
  uint32_t kk0[7], kk1[7];
#pragma unroll
  for (int i = 0; i < 7; ++i) {
    uint32_t o0, o1; tf2x32(0u, 42u, 0u, (uint32_t)i, o0, o1);
    kk0[i] = o0; kk1[i] = o1;
  }

  float h[64];
#pragma unroll
  for (int u = 0; u < 64; ++u) h[u] = hT[u * NROWS + b];

  float lc[3], ls3[3], ll[25];
  // ---- step 0 ----
#pragma unroll
  for (int j = 0; j < 3; ++j) lc[j] = bc[j] + dot64(Wc + j * 64, h);
#pragma unroll
  for (int j = 0; j < 3; ++j) ls3[j] = bs[j] + dot64(Ws + j * 64, h);
#pragma unroll
  for (int j = 0; j < 25; ++j) ll[j] = bl[j] + dot64(Wl + j * 64, h);
  int cs0, ss0, loc0; float clp0, slp0, llp0;
  samp<3>(kk0[0], kk1[0], b, lc, cs0, clp0);
  samp<3>(kk0[1], kk1[1], b, ls3, ss0, slp0);
  samp<25>(kk0[2], kk1[2], b, ll, loc0, llp0);

  const int p0 = min(max(loc0, 0), 24);
  const int t0 = canvas1[b * 100 + p0 * 4 + 0];
  const int t1 = canvas1[b * 100 + p0 * 4 + 1];
  const int t2 = canvas1[b * 100 + p0 * 4 + 2];
  const int t3 = canvas1[b * 100 + p0 * 4 + 3];
  const bool ok0 = (loc0 >= 0) && (loc0 < 25) && (t0 + t1 + t2 + t3 >= 0);
  const float loc_r0 = ok0 ? 1.f : -1.f;
  const float col_r0 = ok0 ? ((cs0 == t0) ? 1.f : -1.f) : 0.f;

  // ---- step 1 ----
#pragma unroll
  for (int u = 0; u < 64; ++u) h[u] = hT[u * NROWS + NB + b];
#pragma unroll
  for (int j = 0; j < 3; ++j) lc[j] = bc[j] + dot64(Wc + j * 64, h);
#pragma unroll
  for (int j = 0; j < 3; ++j) ls3[j] = bs[j] + dot64(Ws + j * 64, h);
  float lp8[8];
#pragma unroll
  for (int j = 0; j < 8; ++j) lp8[j] = bp[j] + dot64(Wp + j * 64, h);
  int cs1, ss1, ls1; float clp1, slp1, llp1;
  samp<3>(kk0[3], kk1[3], b, lc, cs1, clp1);
  samp<3>(kk0[4], kk1[4], b, ls3, ss1, slp1);
  samp<8>(kk0[5], kk1[5], b, lp8, ls1, llp1);

  // attention MLP: hoist h-dependent part out of the 25-position loop
  float uv[32];
#pragma unroll
  for (int j = 0; j < 32; ++j) uv[j] = br1[j] + dot64(Wr1 + j * 68, h);
  float att[25];
  const float b2 = br2[0];
#pragma unroll 1
  for (int p = 0; p < 25; ++p) {
    const float f0 = (float)canvas0[b * 100 + p * 4 + 0];
    const float f1 = (float)canvas0[b * 100 + p * 4 + 1];
    const float f2 = (float)canvas0[b * 100 + p * 4 + 2];
    const float f3 = (float)canvas0[b * 100 + p * 4 + 3];
    float a = b2;
#pragma unroll
    for (int j = 0; j < 32; ++j) {
      float hj = uv[j];
      hj = fmaf(Wr1[j * 68 + 64], f0, hj);
      hj = fmaf(Wr1[j * 68 + 65], f1, hj);
      hj = fmaf(Wr1[j * 68 + 66], f2, hj);
      hj = fmaf(Wr1[j * 68 + 67], f3, hj);
      a = fmaf(Wr2[j], fmaxf(hj, 0.f), a);
    }
    att[p] = a;
  }
  int att_s; float alp1;
  samp<25>(kk0[6], kk1[6], b, att, att_s, alp1);

  const int r0 = canvas0[b * 100 + att_s * 4 + 0];
  const int r1 = canvas0[b * 100 + att_s * 4 + 1];
  const int r2 = canvas0[b * 100 + att_s * 4 + 2];
  const int r3 = canvas0[b * 100 + att_s * 4 + 3];
  const bool match = (r0 == ref[b * 4 + 0]) && (r1 == ref[b * 4 + 1]) &&
                     (r2 == ref[b * 4 + 2]) && (r3 == ref[b * 4 + 3]);
  const float att_reward = match ? 1.f : -1.f;

  // offsets table packed in nibbles (value+1), index ls1
  const int ox = (int)((0x22001120u >> (ls1 * 4)) & 0xFu) - 1;
  const int oy = (int)((0x20200211u >> (ls1 * 4)) & 0xFu) - 1;
  const int loc1 = (r2 + ox) * 5 + (r3 + oy);
  const int p1 = min(max(loc1, 0), 24);
  const int q0 = canvas1[b * 100 + p1 * 4 + 0];
  const int q1 = canvas1[b * 100 + p1 * 4 + 1];
  const int q2 = canvas1[b * 100 + p1 * 4 + 2];
  const int q3 = canvas1[b * 100 + p1 * 4 + 3];
  const bool ok1 = (loc1 >= 0) && (loc1 < 25) && (q0 + q1 + q2 + q3 >= 0);
  const float loc_r1 = ok1 ? 1.f : -1.f;
  const float col_r1 = ok1 ? ((cs1 == q0) ? 1.f : -1.f) : 0.f;

  out[0 * NB + b]  = clp0;
  out[1 * NB + b]  = slp0;
  out[2 * NB + b]  = llp0;
  out[3 * NB + b]  = clp1;
  out[4 * NB + b]  = slp1;
  out[5 * NB + b]  = llp1;
  out[6 * NB + b]  = alp1;
  out[7 * NB + b]  = loc_r0;
  out[8 * NB + b]  = col_r0;
  out[9 * NB + b]  = loc_r0;
  out[10 * NB + b] = loc_r1;
  out[11 * NB + b] = col_r1;
  out[12 * NB + b] = loc_r1;
  out[13 * NB + b] = att_reward;
}

extern "C" void kernel_launch(void* const* d_in, const int* in_sizes, int n_in,
                              void* d_out, int out_size, void* d_ws, size_t ws_size,
                              hipStream_t stream) {
  const int* inst0 = (const int*)d_in[0];
  const int* inst1 = (const int*)d_in[1];
  const int* canvas0 = (const int*)d_in[2];
  const int* canvas1 = (const int*)d_in[3];
  const int* ref = (const int*)d_in[4];
  const float* embed = (const float*)d_in[5];
  const float* W_ih = (const float*)d_in[6];
  const float* W_hh = (const float*)d_in[7];
  const float* b_ih = (const float*)d_in[8];
  const float* b_hh = (const float*)d_in[9];
  const float* Wc = (const float*)d_in[10];
  const float* bc = (const float*)d_in[11];
  const float* Ws = (const float*)d_in[12];
  const float* bs = (const float*)d_in[13];
  const float* Wl = (const float*)d_in[14];
  const float* bl = (const float*)d_in[15];
  const float* Wr1 = (const float*)d_in[16];
  const float* br1 = (const float*)d_in[17];
  const float* Wr2 = (const float*)d_in[18];
  const float* br2 = (const float*)d_in[19];
  const float* Wp = (const float*)d_in[20];
  const float* bp = (const float*)d_in[21];

  float* ws = (float*)d_ws;
  float* embedW = ws;                    // 1001*256
  float* WT = embedW + NV * 256;         // 64*256
  float* hT = WT + 64 * 256;             // 64*32768
  float* out = (float*)d_out;

  k_prep<<<NV + 64, 256, 0, stream>>>(embed, W_ih, W_hh, b_ih, b_hh, embedW, WT);
  k_lstm<<<512, 512, 0, stream>>>(inst0, inst1, embedW, WT, hT);
  k_heads<<<NB / 256, 256, 0, stream>>>(canvas0, canvas1, ref, Wc, bc, Ws, bs,
                                        Wl, bl, Wr1, br1, Wr2, br2, Wp, bp, hT, out);
}

// Round 2
// 790.440 us; speedup vs baseline: 1.0546x; 1.0546x over previous
//
#include <hip/hip_runtime.h>
#include <stdint.h>
#include <math.h>

#define NB 16384      // batch
#define NSEQ 32       // sequence length
#define NV 1001       // vocab (V+1)
#define NROWS 32768   // 2 * NB flattened rows

// ---------------- threefry2x32 (JAX-exact) ----------------
__device__ __forceinline__ void tf2x32(uint32_t k0, uint32_t k1,
                                       uint32_t x0, uint32_t x1,
                                       uint32_t& o0, uint32_t& o1) {
  const uint32_t ks0 = k0, ks1 = k1, ks2 = k0 ^ k1 ^ 0x1BD11BDAu;
  x0 += ks0; x1 += ks1;
  const int rA[4] = {13, 15, 26, 6};
  const int rB[4] = {17, 29, 16, 24};
#pragma unroll
  for (int i = 0; i < 4; ++i) { x0 += x1; x1 = (x1 << rA[i]) | (x1 >> (32 - rA[i])); x1 ^= x0; }
  x0 += ks1; x1 += ks2 + 1u;
#pragma unroll
  for (int i = 0; i < 4; ++i) { x0 += x1; x1 = (x1 << rB[i]) | (x1 >> (32 - rB[i])); x1 ^= x0; }
  x0 += ks2; x1 += ks0 + 2u;
#pragma unroll
  for (int i = 0; i < 4; ++i) { x0 += x1; x1 = (x1 << rA[i]) | (x1 >> (32 - rA[i])); x1 ^= x0; }
  x0 += ks0; x1 += ks1 + 3u;
#pragma unroll
  for (int i = 0; i < 4; ++i) { x0 += x1; x1 = (x1 << rB[i]) | (x1 >> (32 - rB[i])); x1 ^= x0; }
  x0 += ks1; x1 += ks2 + 4u;
#pragma unroll
  for (int i = 0; i < 4; ++i) { x0 += x1; x1 = (x1 << rA[i]) | (x1 >> (32 - rA[i])); x1 ^= x0; }
  o0 = x0 + ks2; o1 = x1 + ks0 + 5u;
}

__device__ __forceinline__ float gumbel_from_bits(uint32_t bits) {
  uint32_t fb = (bits >> 9) | 0x3f800000u;
  float u = __uint_as_float(fb) - 1.0f;
  u = fmaxf(u, 1.17549435e-38f);
  return -logf(-logf(u));
}

template <int C>
__device__ __forceinline__ void samp(uint32_t k0, uint32_t k1, int b,
                                     const float* logits, int& sOut, float& lpOut) {
  float m = -3.4e38f;
#pragma unroll
  for (int c = 0; c < C; ++c) m = fmaxf(m, logits[c]);
  float se = 0.f;
#pragma unroll
  for (int c = 0; c < C; ++c) se += expf(logits[c] - m);
  const float lse = logf(se);
  int best = 0; float bz = -3.4e38f, bl = 0.f;
#pragma unroll
  for (int c = 0; c < C; ++c) {
    uint32_t o0, o1; tf2x32(k0, k1, 0u, (uint32_t)(b * C + c), o0, o1);
    float z = logits[c] + gumbel_from_bits(o0 ^ o1);
    if (z > bz) { bz = z; best = c; bl = logits[c]; }
  }
  sOut = best;
  lpOut = (bl - m) - lse;
}

__device__ __forceinline__ float sigm(float x) { return 1.0f / (1.0f + __expf(-x)); }
__device__ __forceinline__ float tanh_(float x) {
  float e = __expf(2.0f * x);
  return 1.0f - 2.0f / (e + 1.0f);
}

__device__ __forceinline__ float dot64(const float* __restrict__ w, const float* h) {
  float a = 0.f;
#pragma unroll
  for (int k = 0; k < 64; ++k) a = fmaf(w[k], h[k], a);
  return a;
}

// ---------------- kernel A: embedW precompute + W_hh pack ----------------
// embedW[v][j] = b_ih[j] + b_hh[j] + sum_k embed[v][k]*W_ih[j][k]
// WTp[(k*8 + w)*32 + g*8 + i] = W_hh[(g*64 + w*8 + i)*64 + k]  (per-wave contiguous)
__global__ __launch_bounds__(256) void k_prep(
    const float* __restrict__ embed, const float* __restrict__ W_ih,
    const float* __restrict__ W_hh, const float* __restrict__ b_ih,
    const float* __restrict__ b_hh, float* __restrict__ embedW,
    float* __restrict__ WTp) {
  if (blockIdx.x >= NV) {
    int idx = (blockIdx.x - NV) * 256 + threadIdx.x;  // 0..16383
    int k = idx >> 8, rem = idx & 255;
    int w = rem >> 5, j = rem & 31, g = j >> 3, i = j & 7;
    WTp[idx] = W_hh[(g * 64 + w * 8 + i) * 64 + k];
    return;
  }
  __shared__ float er[64];
  int v = blockIdx.x;
  if (threadIdx.x < 64) er[threadIdx.x] = embed[v * 64 + threadIdx.x];
  __syncthreads();
  int j = threadIdx.x;
  float a = b_ih[j] + b_hh[j];
#pragma unroll
  for (int k = 0; k < 64; ++k) a = fmaf(W_ih[j * 64 + k], er[k], a);
  embedW[v * 256 + j] = a;
}

// ---------------- kernel B: LSTM ----------------
// 512 WGs x 512 threads. WG covers 64 rows (lane=row). Wave w owns units [8w,8w+8).
// Double-buffered h in LDS (1 barrier/step). h chunk loaded to VGPRs before the
// FMA stream so s_load weights pipeline without ds_read lgkm interference.
// embedW row for step t+1 prefetched during step t's FMA loop.
__global__ __launch_bounds__(512, 4) void k_lstm(
    const int* __restrict__ inst0, const int* __restrict__ inst1,
    const float* __restrict__ embedW, const float* __restrict__ WTp,
    float* __restrict__ hT) {
  __shared__ float hb[2][64 * 64];  // 32 KB
  const int tid = threadIdx.x;
  const int lane = tid & 63;
  const int wave = __builtin_amdgcn_readfirstlane(tid >> 6);
  const int u0 = wave * 8;
  const int flat = blockIdx.x * 64 + lane;
  const int s = blockIdx.x >> 8;
  const int b = flat & (NB - 1);
  const int* __restrict__ inst = s ? inst1 : inst0;

  for (int i = tid; i < 64 * 64; i += 512) hb[0][i] = 0.f;
  float c[8];
#pragma unroll
  for (int i = 0; i < 8; ++i) c[i] = 0.f;

  // preload vocab ids (int4 group) and first embedW row
  int4 vg = *reinterpret_cast<const int4*>(inst + b * NSEQ);
  float4 pf[8];
  {
    const float* er = embedW + vg.x * 256 + u0;
#pragma unroll
    for (int g = 0; g < 4; ++g) {
      pf[2 * g]     = *reinterpret_cast<const float4*>(er + g * 64);
      pf[2 * g + 1] = *reinterpret_cast<const float4*>(er + g * 64 + 4);
    }
  }
  __syncthreads();

  int cur = 0;
#pragma unroll 1
  for (int t = 0; t < NSEQ; ++t) {
    // acc init from prefetched embedW row; mapping j = g*8 + i
    float acc[32];
#pragma unroll
    for (int g = 0; g < 4; ++g) {
      acc[g * 8 + 0] = pf[2 * g].x;     acc[g * 8 + 1] = pf[2 * g].y;
      acc[g * 8 + 2] = pf[2 * g].z;     acc[g * 8 + 3] = pf[2 * g].w;
      acc[g * 8 + 4] = pf[2 * g + 1].x; acc[g * 8 + 5] = pf[2 * g + 1].y;
      acc[g * 8 + 6] = pf[2 * g + 1].z; acc[g * 8 + 7] = pf[2 * g + 1].w;
    }
    // prefetch next step's embedW row (hides under the FMA loop)
    const int tn = t + 1;
    if (tn < NSEQ) {
      if ((tn & 3) == 0) vg = *reinterpret_cast<const int4*>(inst + b * NSEQ + tn);
      const int vv = ((tn & 3) == 0) ? vg.x
                   : ((tn & 3) == 1) ? vg.y
                   : ((tn & 3) == 2) ? vg.z : vg.w;
      const float* er = embedW + vv * 256 + u0;
#pragma unroll
      for (int g = 0; g < 4; ++g) {
        pf[2 * g]     = *reinterpret_cast<const float4*>(er + g * 64);
        pf[2 * g + 1] = *reinterpret_cast<const float4*>(er + g * 64 + 4);
      }
    }
    const float* __restrict__ wb = WTp + wave * 32;
#pragma unroll 1
    for (int half = 0; half < 2; ++half) {
      float vh[32];
#pragma unroll
      for (int k = 0; k < 32; ++k) vh[k] = hb[cur][(half * 32 + k) * 64 + lane];
#pragma unroll
      for (int k = 0; k < 32; ++k) {
        const float* __restrict__ w = wb + (half * 32 + k) * 256;
#pragma unroll
        for (int j = 0; j < 32; ++j) acc[j] = fmaf(w[j], vh[k], acc[j]);
      }
    }
#pragma unroll
    for (int i = 0; i < 8; ++i) {
      const float iv = acc[i], fv = acc[8 + i], gv = acc[16 + i], ov = acc[24 + i];
      const float ci = sigm(fv) * c[i] + sigm(iv) * tanh_(gv);
      c[i] = ci;
      hb[cur ^ 1][(u0 + i) * 64 + lane] = sigm(ov) * tanh_(ci);
    }
    __syncthreads();
    cur ^= 1;
  }
#pragma unroll
  for (int i = 0; i < 8; ++i)
    hT[(u0 + i) * NROWS + flat] = hb[cur][(u0 + i) * 64 + lane];
}

// ---------------- kernel C: heads + sampling + rewards ----------------
// 512 WGs x 64 threads; even blocks do dialog step 0, odd blocks step 1.
__global__ __launch_bounds__(64) void k_heads(
    const int* __restrict__ canvas0, const int* __restrict__ canvas1,
    const int* __restrict__ ref,
    const float* __restrict__ Wc, const float* __restrict__ bc,
    const float* __restrict__ Ws, const float* __restrict__ bs,
    const float* __restrict__ Wl, const float* __restrict__ bl,
    const float* __restrict__ Wr1, const float* __restrict__ br1,
    const float* __restrict__ Wr2, const float* __restrict__ br2,
    const float* __restrict__ Wp, const float* __restrict__ bp,
    const float* __restrict__ hT, float* __restrict__ out) {
  const int s = blockIdx.x & 1;
  const int b = (blockIdx.x >> 1) * 64 + threadIdx.x;

  uint32_t kk0[7], kk1[7];
#pragma unroll
  for (int i = 0; i < 7; ++i) {
    uint32_t o0, o1; tf2x32(0u, 42u, 0u, (uint32_t)i, o0, o1);
    kk0[i] = o0; kk1[i] = o1;
  }

  float h[64];
#pragma unroll
  for (int u = 0; u < 64; ++u) h[u] = hT[u * NROWS + s * NB + b];

  float lc[3], ls3[3];
#pragma unroll
  for (int j = 0; j < 3; ++j) lc[j] = bc[j] + dot64(Wc + j * 64, h);
#pragma unroll
  for (int j = 0; j < 3; ++j) ls3[j] = bs[j] + dot64(Ws + j * 64, h);

  if (s == 0) {
    float ll[25];
#pragma unroll
    for (int j = 0; j < 25; ++j) ll[j] = bl[j] + dot64(Wl + j * 64, h);
    int cs0, ss0, loc0; float clp0, slp0, llp0;
    samp<3>(kk0[0], kk1[0], b, lc, cs0, clp0);
    samp<3>(kk0[1], kk1[1], b, ls3, ss0, slp0);
    samp<25>(kk0[2], kk1[2], b, ll, loc0, llp0);

    const int p0 = min(max(loc0, 0), 24);
    const int4 pt = reinterpret_cast<const int4*>(canvas1 + b * 100)[p0];
    const bool ok0 = (loc0 >= 0) && (loc0 < 25) && (pt.x + pt.y + pt.z + pt.w >= 0);
    const float loc_r0 = ok0 ? 1.f : -1.f;
    const float col_r0 = ok0 ? ((cs0 == pt.x) ? 1.f : -1.f) : 0.f;

    out[0 * NB + b] = clp0;
    out[1 * NB + b] = slp0;
    out[2 * NB + b] = llp0;
    out[7 * NB + b] = loc_r0;
    out[8 * NB + b] = col_r0;
    out[9 * NB + b] = loc_r0;
  } else {
    float lp8[8];
#pragma unroll
    for (int j = 0; j < 8; ++j) lp8[j] = bp[j] + dot64(Wp + j * 64, h);
    int cs1, ss1, ls1; float clp1, slp1, llp1;
    samp<3>(kk0[3], kk1[3], b, lc, cs1, clp1);
    samp<3>(kk0[4], kk1[4], b, ls3, ss1, slp1);
    samp<8>(kk0[5], kk1[5], b, lp8, ls1, llp1);

    float uv[32];
#pragma unroll
    for (int j = 0; j < 32; ++j) uv[j] = br1[j] + dot64(Wr1 + j * 68, h);
    float att[25];
    const float b2 = br2[0];
#pragma unroll 1
    for (int p = 0; p < 25; ++p) {
      const int4 c4 = reinterpret_cast<const int4*>(canvas0 + b * 100)[p];
      const float f0 = (float)c4.x, f1 = (float)c4.y;
      const float f2 = (float)c4.z, f3 = (float)c4.w;
      float a = b2;
#pragma unroll
      for (int j = 0; j < 32; ++j) {
        float hj = uv[j];
        hj = fmaf(Wr1[j * 68 + 64], f0, hj);
        hj = fmaf(Wr1[j * 68 + 65], f1, hj);
        hj = fmaf(Wr1[j * 68 + 66], f2, hj);
        hj = fmaf(Wr1[j * 68 + 67], f3, hj);
        a = fmaf(Wr2[j], fmaxf(hj, 0.f), a);
      }
      att[p] = a;
    }
    int att_s; float alp1;
    samp<25>(kk0[6], kk1[6], b, att, att_s, alp1);

    const int4 r4 = reinterpret_cast<const int4*>(canvas0 + b * 100)[att_s];
    const int4 rr = *reinterpret_cast<const int4*>(ref + b * 4);
    const bool match = (r4.x == rr.x) && (r4.y == rr.y) && (r4.z == rr.z) && (r4.w == rr.w);
    const float att_reward = match ? 1.f : -1.f;

    const int ox = (int)((0x22001120u >> (ls1 * 4)) & 0xFu) - 1;
    const int oy = (int)((0x20200211u >> (ls1 * 4)) & 0xFu) - 1;
    const int loc1 = (r4.z + ox) * 5 + (r4.w + oy);
    const int p1 = min(max(loc1, 0), 24);
    const int4 q4 = reinterpret_cast<const int4*>(canvas1 + b * 100)[p1];
    const bool ok1 = (loc1 >= 0) && (loc1 < 25) && (q4.x + q4.y + q4.z + q4.w >= 0);
    const float loc_r1 = ok1 ? 1.f : -1.f;
    const float col_r1 = ok1 ? ((cs1 == q4.x) ? 1.f : -1.f) : 0.f;

    out[3 * NB + b]  = clp1;
    out[4 * NB + b]  = slp1;
    out[5 * NB + b]  = llp1;
    out[6 * NB + b]  = alp1;
    out[10 * NB + b] = loc_r1;
    out[11 * NB + b] = col_r1;
    out[12 * NB + b] = loc_r1;
    out[13 * NB + b] = att_reward;
  }
}

extern "C" void kernel_launch(void* const* d_in, const int* in_sizes, int n_in,
                              void* d_out, int out_size, void* d_ws, size_t ws_size,
                              hipStream_t stream) {
  const int* inst0 = (const int*)d_in[0];
  const int* inst1 = (const int*)d_in[1];
  const int* canvas0 = (const int*)d_in[2];
  const int* canvas1 = (const int*)d_in[3];
  const int* ref = (const int*)d_in[4];
  const float* embed = (const float*)d_in[5];
  const float* W_ih = (const float*)d_in[6];
  const float* W_hh = (const float*)d_in[7];
  const float* b_ih = (const float*)d_in[8];
  const float* b_hh = (const float*)d_in[9];
  const float* Wc = (const float*)d_in[10];
  const float* bc = (const float*)d_in[11];
  const float* Ws = (const float*)d_in[12];
  const float* bs = (const float*)d_in[13];
  const float* Wl = (const float*)d_in[14];
  const float* bl = (const float*)d_in[15];
  const float* Wr1 = (const float*)d_in[16];
  const float* br1 = (const float*)d_in[17];
  const float* Wr2 = (const float*)d_in[18];
  const float* br2 = (const float*)d_in[19];
  const float* Wp = (const float*)d_in[20];
  const float* bp = (const float*)d_in[21];

  float* ws = (float*)d_ws;
  float* embedW = ws;                    // 1001*256
  float* WTp = embedW + NV * 256;        // 64*256 packed
  float* hT = WTp + 64 * 256;            // 64*32768
  float* out = (float*)d_out;

  k_prep<<<NV + 64, 256, 0, stream>>>(embed, W_ih, W_hh, b_ih, b_hh, embedW, WTp);
  k_lstm<<<512, 512, 0, stream>>>(inst0, inst1, embedW, WTp, hT);
  k_heads<<<512, 64, 0, stream>>>(canvas0, canvas1, ref, Wc, bc, Ws, bs,
                                  Wl, bl, Wr1, br1, Wr2, br2, Wp, bp, hT, out);
}